// Round 1
// 1477.733 us; speedup vs baseline: 1.1697x; 1.1697x over previous
//
#include <hip/hip_runtime.h>
#include <hip/hip_bf16.h>
#include <math.h>

// Problem constants (MambaStack reference)
#define DEPTH   2
#define DM      768      // d_model
#define DS      64       // d_state
#define DC      4        // d_conv
#define DI      1536     // d_inner
#define DTR     48       // dt_rank
#define BATCH   4
#define SEQ     2048
#define MROWS   (BATCH*SEQ)          // 8192
#define XDC     (DTR + 2*DS)         // 176 (xdbl cols)
#define NC      8                    // scan chunks
#define TCH     (SEQ/NC)             // 256 timesteps per chunk
#define LOG2E   1.44269504088896f

typedef __attribute__((ext_vector_type(8))) short bf16x8;
typedef __attribute__((ext_vector_type(4))) float f32x4;
typedef unsigned short ushort_t;
#define GAS __attribute__((address_space(1)))
#define LAS __attribute__((address_space(3)))

__device__ __forceinline__ float silu_fast(float x) {
    return x / (1.f + __expf(-x));
}
__device__ __forceinline__ float softplus_acc(float x) {
    return x > 20.f ? x : log1pf(expf(x));
}

// Split fp32 -> (hi, lo) bf16 pair, both RNE.  hi+lo represents f to ~2^-17.
__device__ __forceinline__ void bf16_split(float f, ushort_t& h, ushort_t& l) {
    unsigned u = __float_as_uint(f);
    unsigned hr = u + 0x7FFF + ((u >> 16) & 1);
    h = (ushort_t)(hr >> 16);
    float lof = f - __uint_as_float((unsigned)h << 16);
    unsigned ul = __float_as_uint(lof);
    unsigned lr = ul + 0x7FFF + ((ul >> 16) & 1);
    l = (ushort_t)(lr >> 16);
}

// Contiguous fp32 array -> hi/lo bf16 planes.  n multiple of 1024.
__global__ __launch_bounds__(256) void split_bf16(
    const float* __restrict__ in, ushort_t* __restrict__ hi,
    ushort_t* __restrict__ lo)
{
    const size_t i = ((size_t)blockIdx.x * 256 + threadIdx.x) * 4;
    const float4 v = *(const float4*)(in + i);
    ushort4 h, l;
    bf16_split(v.x, h.x, l.x); bf16_split(v.y, h.y, l.y);
    bf16_split(v.z, h.z, l.z); bf16_split(v.w, h.w, l.w);
    *(ushort4*)(hi + i) = h;
    *(ushort4*)(lo + i) = l;
}

// ---------------- bf16x2-split MFMA GEMM ----------------
// C[M,N] = (Ah+Al) @ (Wh+Wl)^T, planes bf16, row strides ldA/ldW (elements).
// 128x128 tile, BK=32, 4 waves; 16x16x32 MFMA, 3 per tile (hh, hl, lh).
// If Chi != null, the output is emitted as bf16 hi/lo planes instead of fp32.
// N-guard on the fp32 store path (used with N=176 for x_proj).
__global__ __launch_bounds__(256, 2) void gemm_mfma(
    const ushort_t* __restrict__ Ah, const ushort_t* __restrict__ Al,
    const ushort_t* __restrict__ Wh, const ushort_t* __restrict__ Wl,
    float* __restrict__ C, int N, int K, int ldA, int ldW,
    ushort_t* __restrict__ Chi, ushort_t* __restrict__ Clo)
{
    __shared__ ushort_t lds[4][128 * 32];
    const int tid  = threadIdx.x;
    const int wave = tid >> 6, lane = tid & 63;
    const int bm0 = blockIdx.y * 128, bn0 = blockIdx.x * 128;
    const int wm = (wave >> 1) * 64, wn = (wave & 1) * 64;

    const ushort_t* gp = (wave == 0) ? Ah : (wave == 1) ? Al : (wave == 2) ? Wh : Wl;
    const int ldg = (wave < 2) ? ldA : ldW;
    const int rb = (wave < 2) ? bm0 : bn0;
    const int srow = lane >> 2;           // 0..15
    const int skq  = (lane & 3) * 8;      // k offset in elements

    f32x4 acc[4][4];
#pragma unroll
    for (int i = 0; i < 4; i++)
#pragma unroll
        for (int j = 0; j < 4; j++) acc[i][j] = (f32x4){0.f, 0.f, 0.f, 0.f};

    const int lm  = lane & 15;
    const int kg8 = (lane >> 4) * 8;

    for (int k0 = 0; k0 < K; k0 += 32) {
#pragma unroll
        for (int j = 0; j < 8; j++) {
            const ushort_t* ga = gp + (size_t)(rb + j * 16 + srow) * ldg + k0 + skq;
            __builtin_amdgcn_global_load_lds(
                (const GAS unsigned*)ga, (LAS unsigned*)&lds[wave][j * 512], 16, 0, 0);
        }
        __syncthreads();

        bf16x8 ah[4], al[4], bh[4], bl[4];
#pragma unroll
        for (int i = 0; i < 4; i++) {
            const int ar = (wm + i * 16 + lm) * 32 + kg8;
            ah[i] = *(const bf16x8*)&lds[0][ar];
            al[i] = *(const bf16x8*)&lds[1][ar];
            const int br = (wn + i * 16 + lm) * 32 + kg8;
            bh[i] = *(const bf16x8*)&lds[2][br];
            bl[i] = *(const bf16x8*)&lds[3][br];
        }
#pragma unroll
        for (int mi = 0; mi < 4; mi++)
#pragma unroll
            for (int ni = 0; ni < 4; ni++) {
                f32x4 t = acc[mi][ni];
                t = __builtin_amdgcn_mfma_f32_16x16x32_bf16(al[mi], bh[ni], t, 0, 0, 0);
                t = __builtin_amdgcn_mfma_f32_16x16x32_bf16(ah[mi], bl[ni], t, 0, 0, 0);
                t = __builtin_amdgcn_mfma_f32_16x16x32_bf16(ah[mi], bh[ni], t, 0, 0, 0);
                acc[mi][ni] = t;
            }
        __syncthreads();
    }

#pragma unroll
    for (int mi = 0; mi < 4; mi++)
#pragma unroll
        for (int ni = 0; ni < 4; ni++)
#pragma unroll
            for (int r = 0; r < 4; r++) {
                const int rowg = bm0 + wm + mi * 16 + (lane >> 4) * 4 + r;
                const int colg = bn0 + wn + ni * 16 + lm;
                const float v = acc[mi][ni][r];
                if (Chi) {
                    ushort_t h, l;
                    bf16_split(v, h, l);
                    Chi[(size_t)rowg * N + colg] = h;
                    Clo[(size_t)rowg * N + colg] = l;
                } else if (colg < N) {
                    C[(size_t)rowg * N + colg] = v;
                }
            }
}

// dt GEMM, transposed output: dtT[(b*DI+d)*SEQ + t] =
//   softplus(sum_k Wdt[d][k] * xdbl[b*SEQ+t][k] + bias[d]).
// An NT GEMM with M-dim = d (rows of Wdt), N-dim = t (rows of xdbl), K=48.
// Grid (SEQ/128, DI/128, BATCH).  Fully coalesced stores; kills trans_r2t.
__global__ __launch_bounds__(256, 2) void gemm_dt_T(
    const float* __restrict__ Wdt, const float* __restrict__ xdbl,
    const float* __restrict__ bias, float* __restrict__ dtT)
{
    __shared__ float As[8][132];
    __shared__ float Bs[8][132];
    const int tid = threadIdx.x;
    const int bd0 = blockIdx.y * 128;   // d tile
    const int bt0 = blockIdx.x * 128;   // t tile
    const int b   = blockIdx.z;
    const int tx = tid & 15;            // t group
    const int ty = tid >> 4;            // d group
    const int lrow = tid >> 1;
    const int lk4  = (tid & 1) * 4;

    float acc[8][8];
#pragma unroll
    for (int i = 0; i < 8; i++)
#pragma unroll
        for (int j = 0; j < 8; j++) acc[i][j] = 0.f;

    for (int k0 = 0; k0 < DTR; k0 += 8) {
        const float4 av = *(const float4*)(Wdt + (size_t)(bd0 + lrow) * DTR + k0 + lk4);
        const float4 wv = *(const float4*)(xdbl + ((size_t)b * SEQ + bt0 + lrow) * XDC + k0 + lk4);
        __syncthreads();
        As[lk4 + 0][lrow] = av.x; As[lk4 + 1][lrow] = av.y;
        As[lk4 + 2][lrow] = av.z; As[lk4 + 3][lrow] = av.w;
        Bs[lk4 + 0][lrow] = wv.x; Bs[lk4 + 1][lrow] = wv.y;
        Bs[lk4 + 2][lrow] = wv.z; Bs[lk4 + 3][lrow] = wv.w;
        __syncthreads();
#pragma unroll
        for (int kk = 0; kk < 8; kk++) {
            const float4 a0 = *(const float4*)&As[kk][ty * 8];
            const float4 a1 = *(const float4*)&As[kk][ty * 8 + 4];
            const float4 b0 = *(const float4*)&Bs[kk][tx * 8];
            const float4 b1 = *(const float4*)&Bs[kk][tx * 8 + 4];
            const float ar[8] = {a0.x, a0.y, a0.z, a0.w, a1.x, a1.y, a1.z, a1.w};
            const float br[8] = {b0.x, b0.y, b0.z, b0.w, b1.x, b1.y, b1.z, b1.w};
#pragma unroll
            for (int i = 0; i < 8; i++)
#pragma unroll
                for (int j = 0; j < 8; j++)
                    acc[i][j] = fmaf(ar[i], br[j], acc[i][j]);
        }
    }

#pragma unroll
    for (int i = 0; i < 8; i++) {
        const int d = bd0 + ty * 8 + i;
        const float bb = bias[d];
#pragma unroll
        for (int j4 = 0; j4 < 8; j4 += 4) {
            float4 v = make_float4(acc[i][j4], acc[i][j4 + 1], acc[i][j4 + 2], acc[i][j4 + 3]);
            v.x = softplus_acc(v.x + bb);
            v.y = softplus_acc(v.y + bb);
            v.z = softplus_acc(v.z + bb);
            v.w = softplus_acc(v.w + bb);
            *(float4*)(dtT + ((size_t)b * DI + d) * SEQ + bt0 + tx * 8 + j4) = v;
        }
    }
}

// Depthwise causal conv (K=4) + SiLU -> uT [b][d][t] fp32 AND row-major
// bf16 hi/lo planes (for the x_proj MFMA GEMM).
__global__ __launch_bounds__(256) void conv_silu_T2(
    const float* __restrict__ xz, const float* __restrict__ cw,
    const float* __restrict__ cb, float* __restrict__ uT,
    ushort_t* __restrict__ uh, ushort_t* __restrict__ ul)
{
    __shared__ float tin[67][65];
    __shared__ float ttr[64][65];
    const int tid = threadIdx.x;
    const int d0 = blockIdx.x * 64, t0 = blockIdx.y * 64, b = blockIdx.z;
    const int cl = tid & 63, q = tid >> 6;

    for (int r = q; r < 67; r += 4) {
        const int t = t0 - 3 + r;
        float v = 0.f;
        if (t >= 0) v = xz[((size_t)b * SEQ + t) * (2 * DI) + d0 + cl];
        tin[r][cl] = v;
    }
    __syncthreads();

    const float4 w = ((const float4*)cw)[d0 + cl];
    const float bb = cb[d0 + cl];
#pragma unroll
    for (int i = 0; i < 16; i++) {
        const int t = q * 16 + i;
        float a = bb;
        a = fmaf(tin[t + 0][cl], w.x, a);
        a = fmaf(tin[t + 1][cl], w.y, a);
        a = fmaf(tin[t + 2][cl], w.z, a);
        a = fmaf(tin[t + 3][cl], w.w, a);
        a = silu_fast(a);
        ttr[cl][t] = a;
        ushort_t h, l;
        bf16_split(a, h, l);
        const size_t row = (size_t)b * SEQ + t0 + t;
        uh[row * DI + d0 + cl] = h;          // coalesced in d
        ul[row * DI + d0 + cl] = l;
    }
    __syncthreads();
#pragma unroll
    for (int i = 0; i < 16; i++) {
        const int d = q * 16 + i;
        uT[((size_t)b * DI + d0 + d) * SEQ + t0 + cl] = ttr[d][cl];  // coalesced in t
    }
}

// B/C transpose into lane-interleaved layout:
//   bc4[(b*(SEQ/4) + t/4)*128 + ch] = float4{ x[t..t+3][ch] }
__global__ __launch_bounds__(256) void trans_bc_i4(
    const float* __restrict__ in, float4* __restrict__ bc4)
{
    __shared__ float tile[64][65];
    const int tid = threadIdx.x;
    const int c0 = blockIdx.x * 64, t0 = blockIdx.y * 64, b = blockIdx.z;
    const int cl = tid & 63, q = tid >> 6;
#pragma unroll
    for (int i = 0; i < 16; i++) {
        const int r = q * 16 + i;
        tile[r][cl] = in[((size_t)b * SEQ + t0 + r) * XDC + DTR + c0 + cl];
    }
    __syncthreads();
#pragma unroll
    for (int i = 0; i < 4; i++) {
        const int j = q * 4 + i;
        const float4 v = make_float4(tile[4 * j + 0][cl], tile[4 * j + 1][cl],
                                     tile[4 * j + 2][cl], tile[4 * j + 3][cl]);
        bc4[((size_t)b * (SEQ / 4) + (t0 / 4 + j)) * 128 + c0 + cl] = v;
    }
}

// ---------------- Chunked selective scan ----------------
// s output lives in the dead xz x-half via the linear map
//   addr(L) = (L/1536)*3072 + L%1536,  L = bd*SEQ + t.

#define LOAD4S(DT, UU, BB_, CC_, TB)                                   \
    _Pragma("unroll")                                                  \
    for (int g = 0; g < 4; g++) {                                      \
        DT[g]  = *(const float4*)(dtp + (TB) + 4 * g);                 \
        UU[g]  = *(const float4*)(up + (TB) + 4 * g);                  \
        BB_[g] = Bp[(size_t)((TB) / 4 + g) * 128];                     \
        CC_[g] = Cp[(size_t)((TB) / 4 + g) * 128];                     \
    }

#define P3_BLOCK(DT, UU, BB_, CC_, TBASE)                                                          \
    {                                                                                              \
        float p[16];                                                                               \
        _Pragma("unroll")                                                                          \
        for (int g = 0; g < 4; g++) {                                                              \
            h = fmaf(__builtin_amdgcn_exp2f(DT[g].x * An), h, (DT[g].x * UU[g].x) * BB_[g].x); p[4*g+0] = h * CC_[g].x; \
            h = fmaf(__builtin_amdgcn_exp2f(DT[g].y * An), h, (DT[g].y * UU[g].y) * BB_[g].y); p[4*g+1] = h * CC_[g].y; \
            h = fmaf(__builtin_amdgcn_exp2f(DT[g].z * An), h, (DT[g].z * UU[g].z) * BB_[g].z); p[4*g+2] = h * CC_[g].z; \
            h = fmaf(__builtin_amdgcn_exp2f(DT[g].w * An), h, (DT[g].w * UU[g].w) * BB_[g].w); p[4*g+3] = h * CC_[g].w; \
        }                                                                                          \
        _Pragma("unroll")                                                                          \
        for (int i = 0; i < 16; i++) slab[i * 65 + lane] = p[i];                                   \
        float s = 0.f;                                                                             \
        _Pragma("unroll")                                                                          \
        for (int j = 0; j < 16; j++) s += slab[tt * 65 + seg * 16 + j];                            \
        s += __shfl_xor(s, 16, 64);                                                                \
        s += __shfl_xor(s, 32, 64);                                                                \
        if (lane < 16) sp[(TBASE) + tt] = s;                                                       \
    }

// Truncated-backward chunk-end state:
//   hend = sum_t exp2(An * R_t) * dt_t*u_t*B_t,   R_t = suffix-sum of dt.
// All An < 0 and the weights decay monotonically, so once every lane's
// weight underflows 2^-30 the remaining (earlier) terms are numerically
// irrelevant (<= 256 * 2^-30 * max|dub| ~ 1e-11 abs here).  Typical stop:
// ~32 of 256 steps.  Worst case (tiny dt) runs the full chunk = still exact.
__global__ __launch_bounds__(256, 2) void scan_tail(
    const float* __restrict__ dtT, const float* __restrict__ uT,
    const float4* __restrict__ bc4, const float* __restrict__ A_log,
    float* __restrict__ hend)
{
    const int wid  = __builtin_amdgcn_readfirstlane(
                        (int)((blockIdx.x * 256 + threadIdx.x) >> 6));
    const int lane = threadIdx.x & 63;
    const int c  = wid & (NC - 1);
    const int bd = wid >> 3;
    const int b  = bd / DI;
    const int d  = bd - b * DI;

    const float An = -expf(A_log[d * DS + lane]) * LOG2E;
    const float* dtp = dtT + (size_t)bd * SEQ + c * TCH;
    const float* up  = uT  + (size_t)bd * SEQ + c * TCH;
    const float4* Bp = bc4 + ((size_t)b * (SEQ / 4) + c * (TCH / 4)) * 128 + lane;

    float h = 0.f, r = 0.f;
    for (int tb = TCH - 16; tb >= 0; tb -= 16) {
        float4 dt4[4], u4[4], B4[4];
#pragma unroll
        for (int g = 0; g < 4; g++) {
            dt4[g] = *(const float4*)(dtp + tb + 4 * g);
            u4[g]  = *(const float4*)(up  + tb + 4 * g);
            B4[g]  = Bp[(size_t)(tb / 4 + g) * 128];
        }
#pragma unroll
        for (int g = 3; g >= 0; g--) {
            h = fmaf(__builtin_amdgcn_exp2f(An * r), (dt4[g].w * u4[g].w) * B4[g].w, h); r += dt4[g].w;
            h = fmaf(__builtin_amdgcn_exp2f(An * r), (dt4[g].z * u4[g].z) * B4[g].z, h); r += dt4[g].z;
            h = fmaf(__builtin_amdgcn_exp2f(An * r), (dt4[g].y * u4[g].y) * B4[g].y, h); r += dt4[g].y;
            h = fmaf(__builtin_amdgcn_exp2f(An * r), (dt4[g].x * u4[g].x) * B4[g].x, h); r += dt4[g].x;
        }
        if (__all(An * r < -30.f)) break;   // all remaining weights < 2^-30
    }
    hend[(size_t)wid * DS + lane] = h;
}

// Cross-chunk combine.  Computes per-chunk dt sums itself (dt is
// wave-uniform per channel: lane l sums its own 32-step segment, 3-stage
// shfl_xor reduce within 8-lane groups = one chunk each), then
//   h0[c] = state entering chunk c;  h <- exp2(An*sdt_c)*h + hend[c].
__global__ __launch_bounds__(256) void scan_phase2(
    const float* __restrict__ dtT, const float* __restrict__ A_log,
    const float* __restrict__ hend, float* __restrict__ h0out)
{
    const int bd   = (blockIdx.x * 256 + threadIdx.x) >> 6;
    const int lane = threadIdx.x & 63;
    const int d    = bd % DI;

    const float* dtp = dtT + (size_t)bd * SEQ + lane * 32;
    float s = 0.f;
#pragma unroll
    for (int g = 0; g < 8; g++) {
        const float4 v = *(const float4*)(dtp + 4 * g);
        s += (v.x + v.y) + (v.z + v.w);
    }
    s += __shfl_xor(s, 1, 64);
    s += __shfl_xor(s, 2, 64);
    s += __shfl_xor(s, 4, 64);   // lanes 8c..8c+7 all hold chunk-c sum

    const float An = -expf(A_log[d * DS + lane]) * LOG2E;
    float h = 0.f;
#pragma unroll
    for (int c = 0; c < NC; c++) {
        const float sdt = __shfl(s, 8 * c, 64);
        const size_t off = ((size_t)bd * NC + c) * DS + lane;
        h0out[off] = h;
        h = fmaf(__builtin_amdgcn_exp2f(An * sdt), h, hend[off]);
    }
}

__global__ __launch_bounds__(256, 2) void scan_phase3(
    const float* __restrict__ dtT, const float* __restrict__ uT,
    const float4* __restrict__ bc4, const float* __restrict__ A_log,
    const float* __restrict__ hin, float* __restrict__ sX)
{
    __shared__ float red[4][16 * 65];
    const int wid  = __builtin_amdgcn_readfirstlane(
                        (int)((blockIdx.x * 256 + threadIdx.x) >> 6));
    const int lane = threadIdx.x & 63;
    const int c  = wid & (NC - 1);
    const int bd = wid >> 3;
    const int b  = bd / DI;
    const int d  = bd - b * DI;

    const float An = -expf(A_log[d * DS + lane]) * LOG2E;
    const float* dtp = dtT + (size_t)bd * SEQ + c * TCH;
    const float* up  = uT  + (size_t)bd * SEQ + c * TCH;
    const float4* Bp = bc4 + ((size_t)b * (SEQ / 4) + c * (TCH / 4)) * 128 + lane;
    const float4* Cp = Bp + 64;
    const size_t L0 = (size_t)bd * SEQ + c * TCH;
    float* sp = sX + (L0 / 1536) * 3072 + (L0 % 1536);
    float* slab = &red[threadIdx.x >> 6][0];
    const int tt = lane & 15, seg = lane >> 4;

    float4 dA4[4], uA4[4], BA4[4], CA4[4], dB4[4], uB4[4], BB4[4], CB4[4];
    LOAD4S(dA4, uA4, BA4, CA4, 0);

    float h = hin[(size_t)wid * DS + lane];
    for (int tb = 0; tb < TCH; tb += 32) {
        LOAD4S(dB4, uB4, BB4, CB4, tb + 16);
        P3_BLOCK(dA4, uA4, BA4, CA4, tb);
        LOAD4S(dA4, uA4, BA4, CA4, tb + 32);   // final iter overreads (safe)
        P3_BLOCK(dB4, uB4, BB4, CB4, tb + 16);
    }
}

// Fused gate + transpose + bf16-split:
//   y = (s + D*u) * silu(z), emitted directly as row-major bf16 planes yh/yl.
// s read from the mapped xz x-half, u from uT, z from xz z-half (LDS tile).
__global__ __launch_bounds__(256) void gate_split_T(
    const float* __restrict__ xz, const float* __restrict__ uT,
    const float* __restrict__ Dskip,
    ushort_t* __restrict__ yh, ushort_t* __restrict__ yl)
{
    __shared__ float zt[64][65];   // [t][d]
    __shared__ float yt[64][65];   // [d][t]
    const int tid = threadIdx.x;
    const int d0 = blockIdx.x * 64, t0 = blockIdx.y * 64, b = blockIdx.z;
    const int cl = tid & 63, q = tid >> 6;
#pragma unroll
    for (int i = 0; i < 16; i++) {
        const int r = q * 16 + i;
        zt[r][cl] = xz[((size_t)b * SEQ + t0 + r) * (2 * DI) + DI + d0 + cl];
    }
    __syncthreads();
#pragma unroll
    for (int i = 0; i < 16; i++) {
        const int dd = q * 16 + i;
        const size_t Lrow = ((size_t)b * DI + d0 + dd) * SEQ + t0;
        const float s = xz[(Lrow / 1536) * 3072 + (Lrow % 1536) + cl];
        const float u = uT[Lrow + cl];
        const float Dd = Dskip[d0 + dd];   // wave-uniform
        yt[dd][cl] = (s + Dd * u) * silu_fast(zt[cl][dd]);
    }
    __syncthreads();
#pragma unroll
    for (int i = 0; i < 16; i++) {
        const int t = q * 16 + i;
        ushort_t h, l;
        bf16_split(yt[cl][t], h, l);
        const size_t row = (size_t)b * SEQ + t0 + t;
        yh[row * DI + d0 + cl] = h;        // coalesced in d
        yl[row * DI + d0 + cl] = l;
    }
}

extern "C" void kernel_launch(void* const* d_in, const int* in_sizes, int n_in,
                              void* d_out, int out_size, void* d_ws, size_t ws_size,
                              hipStream_t stream) {
    (void)in_sizes; (void)n_in; (void)out_size; (void)ws_size;
    const float* x    = (const float*)d_in[0];
    const float* Wi   = (const float*)d_in[1];
    const float* cw   = (const float*)d_in[2];
    const float* cb   = (const float*)d_in[3];
    const float* Wx   = (const float*)d_in[4];
    const float* Wdt  = (const float*)d_in[5];
    const float* bdt  = (const float*)d_in[6];
    const float* Alog = (const float*)d_in[7];
    const float* Dsk  = (const float*)d_in[8];
    const float* Wo   = (const float*)d_in[9];
    float* out = (float*)d_out;

    // Workspace (fp32) regions:
    float* xz    = (float*)d_ws;                          // [MROWS, 3072]: x-half xpart -> s(mapped); z-half z
    float* uT    = xz    + (size_t)MROWS * (2 * DI);      // sh/sl planes -> u fp32 -> sh/sl again (layer0 out)
    float* dtT   = uT    + (size_t)MROWS * DI;            // wih/wil -> uh/ul -> dt -> yl (upper half)
    float* xdbl  = dtT   + (size_t)MROWS * DI;            // x_proj C fp32; later woh/wol arena
    float* bcT   = xdbl  + (size_t)MROWS * XDC;           // wxh/wxl (padded) -> bc4 interleaved
    float* xnext = bcT   + (size_t)BATCH * 128 * SEQ;     // hend/h0 -> yh
    float* hend  = xnext;                                 // [B*DI*NC, DS]
    float* h0buf = xnext + (size_t)BATCH * DI * NC * DS;  // [B*DI*NC, DS]

    // bf16 plane homes (all lifetimes disjoint on the serial stream):
    ushort_t* sh  = (ushort_t*)uT;                        // [MROWS, DM] x2 (layer input planes)
    ushort_t* sl  = sh  + (size_t)MROWS * DM;
    ushort_t* wih = (ushort_t*)(dtT + (size_t)MROWS * DM);// [2*DI, DM] x2, dtT upper half
    ushort_t* wil = wih + (size_t)2 * DI * DM;
    ushort_t* uh  = (ushort_t*)dtT;                       // [MROWS, DI] x2 fills dtT region
    ushort_t* ul  = uh  + (size_t)MROWS * DI;
    ushort_t* wxh = (ushort_t*)bcT;                       // [256(pad), DI] x2 in bcT
    ushort_t* wxl = wxh + (size_t)256 * DI;
    ushort_t* woh = (ushort_t*)xdbl;                      // [DM, DI] x2
    ushort_t* wol = woh + (size_t)DM * DI;
    ushort_t* yh  = (ushort_t*)xnext;                     // [MROWS, DI]
    ushort_t* yl  = (ushort_t*)(dtT + (size_t)MROWS * DM);// [MROWS, DI], dtT upper half

    for (int i = 0; i < DEPTH; i++) {
        const float* Wi_l   = Wi   + (size_t)i * 2 * DI * DM;
        const float* cw_l   = cw   + (size_t)i * DI * DC;
        const float* cb_l   = cb   + (size_t)i * DI;
        const float* Wx_l   = Wx   + (size_t)i * XDC * DI;
        const float* Wdt_l  = Wdt  + (size_t)i * DI * DTR;
        const float* bdt_l  = bdt  + (size_t)i * DI;
        const float* Alog_l = Alog + (size_t)i * DI * DS;
        const float* Dsk_l  = Dsk  + (size_t)i * DI;
        const float* Wo_l   = Wo   + (size_t)i * DM * DI;

        // 1. input planes: layer 0 splits x; layer 1 already has sh/sl
        //    (emitted by layer 0's out-GEMM epilogue).
        if (i == 0)
            split_bf16<<<(size_t)MROWS * DM / 1024, 256, 0, stream>>>(x, sh, sl);
        split_bf16<<<(size_t)2 * DI * DM / 1024, 256, 0, stream>>>(Wi_l, wih, wil);
        // 2. xz = src @ Wi^T  (bf16x2 MFMA)        [8192, 3072]
        gemm_mfma<<<dim3(2 * DI / 128, MROWS / 128), 256, 0, stream>>>(
            sh, sl, wih, wil, xz, 2 * DI, DM, DM, DM, nullptr, nullptr);
        // 3. u = silu(conv(xz[:, :DI])) -> uT fp32 + uh/ul planes (dtT region)
        conv_silu_T2<<<dim3(DI / 64, SEQ / 64, BATCH), 256, 0, stream>>>(
            xz, cw_l, cb_l, uT, uh, ul);
        // 4. Wx planes (bcT region, 256-row padded; pad rows finite garbage)
        split_bf16<<<(size_t)XDC * DI / 1024, 256, 0, stream>>>(Wx_l, wxh, wxl);
        // 5. xdbl = u @ Wx^T  (bf16x2 MFMA, N=176 guarded)
        gemm_mfma<<<dim3((XDC + 127) / 128, MROWS / 128), 256, 0, stream>>>(
            uh, ul, wxh, wxl, xdbl, XDC, DI, DI, DI, nullptr, nullptr);
        // 6. B/C -> lane-interleaved bc4 layout (overwrites wxh/wxl, dead)
        trans_bc_i4<<<dim3(2, SEQ / 64, BATCH), 256, 0, stream>>>(
            xdbl, (float4*)bcT);
        // 7. dtT = softplus(Wdt @ xdbl_dt^T + bdt)  — direct transposed output
        gemm_dt_T<<<dim3(SEQ / 128, DI / 128, BATCH), 256, 0, stream>>>(
            Wdt_l, xdbl, bdt_l, dtT);
        // 8. truncated-backward chunk-end states
        scan_tail<<<(BATCH * DI * NC) / 4, 256, 0, stream>>>(
            dtT, uT, (const float4*)bcT, Alog_l, hend);
        // 9. cross-chunk combine (computes per-chunk dt sums internally)
        scan_phase2<<<(BATCH * DI) / 4, 256, 0, stream>>>(
            dtT, Alog_l, hend, h0buf);
        // 10. full scan with outputs; writes s into xz x-half (mapped)
        scan_phase3<<<(BATCH * DI * NC) / 4, 256, 0, stream>>>(
            dtT, uT, (const float4*)bcT, Alog_l, h0buf, xz);
        // 11. fused gate + split -> yh (xnext) / yl (dtT upper, dt dead)
        gate_split_T<<<dim3(DI / 64, SEQ / 64, BATCH), 256, 0, stream>>>(
            xz, uT, Dsk_l, yh, yl);
        // 12. Wo planes (xdbl region, dead)
        split_bf16<<<(size_t)DM * DI / 1024, 256, 0, stream>>>(Wo_l, woh, wol);
        // 13. out = y @ Wo^T  (bf16x2 MFMA); layer 0 emits planes sh/sl
        //     directly (consumed by layer 1's step 2), layer 1 emits fp32.
        if (i == DEPTH - 1)
            gemm_mfma<<<dim3(DM / 128, MROWS / 128), 256, 0, stream>>>(
                yh, yl, woh, wol, out, DM, DI, DI, DI, nullptr, nullptr);
        else
            gemm_mfma<<<dim3(DM / 128, MROWS / 128), 256, 0, stream>>>(
                yh, yl, woh, wol, xz /*unused*/, DM, DI, DI, DI, sh, sl);
    }
}